// Round 1
// 1480.211 us; speedup vs baseline: 1.0865x; 1.0865x over previous
//
#include <hip/hip_runtime.h>
#include <stdint.h>

// JAX jax_threefry_partitionable=True semantics (verified exact, rounds 1-9).
// Round-11: scan-side register pipelining. Previous structure: one H row per
// 1024-thread block, 1 block/CU (VGPR>64 from fused sim branch) => only 40 KB
// in flight per CU and ~50% HBM duty cycle (LDS phase + __syncthreads vmcnt(0)
// drains have zero outstanding loads) => scan capped ~2-2.5 TB/s.
// Now each scan block owns 5 consecutive rows (same t since EE%5==0): all 15
// float4 loads issued upfront (60 data VGPRs, statically indexed), rows
// processed back-to-back with LDS-only barriers (no vmcnt drain between rows),
// a single end-of-block vmcnt(0) drain and ONE fetch_add(cnt[t], +5).
// 200 KB in flight/CU, ~100% duty cycle => scan should be HBM-bound (~190 us).
// Sim role (block 0) unchanged from R9/R10 (verified).
constexpr int NN = 10000;          // nodes
constexpr int EE = 1000;           // hyperedges
constexpr int TT = 30;             // output rows
constexpr int TS = TT - 1;         // simulated steps
constexpr int ROW = NN * 3;        // floats per output row
constexpr int S_OFF = TT * ROW;    // state section offset in d_out
constexpr int CAP_E = 48;          // max nodes per edge (P(>=48) ~ 1e-30)
constexpr int WPR = CAP_E / 2;     // packed uint32 words per edge row
constexpr int PREW = 8;            // words prefetched unconditionally (covers ec<=16, ~97%)
constexpr int SIMT = 1024;         // block size (16 waves)
constexpr int NPT  = 10;           // nodes per thread, strided mapping n = tid + k*SIMT
constexpr int RBLK = (NN + SIMT - 1) / SIMT;  // 10 rand-duty rows per step
constexpr int RPB  = 5;            // H rows per scan block (EE % RPB == 0 => one t per block)
static_assert(EE % RPB == 0, "rows of a block must share one t");

// ---- Threefry-2x32, 20 rounds (exact JAX semantics), host+device ----
__host__ __device__ inline void tf2x32(uint32_t k0, uint32_t k1,
                                       uint32_t x0, uint32_t x1,
                                       uint32_t &o0, uint32_t &o1) {
  uint32_t ks2 = k0 ^ k1 ^ 0x1BD11BDAu;
  x0 += k0; x1 += k1;
#define TFR(r) do { x0 += x1; x1 = (x1 << (r)) | (x1 >> (32 - (r))); x1 ^= x0; } while (0)
  TFR(13); TFR(15); TFR(26); TFR(6);
  x0 += k1;  x1 += ks2 + 1u;
  TFR(17); TFR(29); TFR(16); TFR(24);
  x0 += ks2; x1 += k0 + 2u;
  TFR(13); TFR(15); TFR(26); TFR(6);
  x0 += k0;  x1 += k1 + 3u;
  TFR(17); TFR(29); TFR(16); TFR(24);
  x0 += k1;  x1 += ks2 + 4u;
  TFR(13); TFR(15); TFR(26); TFR(6);
  x0 += ks2; x1 += k0 + 5u;
#undef TFR
  o0 = x0; o1 = x1;
}

__device__ inline float bits_to_uniform(uint32_t bits) {
  float f = __uint_as_float((bits >> 9) | 0x3F800000u) - 1.0f;
  return f < 0.f ? 0.f : f;
}

struct StepKeys { uint32_t k1a[TS], k1b[TS], k2a[TS], k2b[TS]; };

// LDS-only barrier: orders LDS ops without draining global loads/stores (vmcnt).
__device__ inline void bar_lds() {
  asm volatile("s_waitcnt lgkmcnt(0)\n\ts_barrier" ::: "memory");
}

#define ALD(p)    __hip_atomic_load((p),  __ATOMIC_RELAXED, __HIP_MEMORY_SCOPE_AGENT)
#define AST(p, v) __hip_atomic_store((p), (v), __ATOMIC_RELAXED, __HIP_MEMORY_SCOPE_AGENT)

// cnt is in d_ws (poisoned 0xAA every replay): must be zeroed before k_fused.
__global__ void k_zero(unsigned* __restrict__ cnt) {
  if (threadIdx.x < TS) cnt[threadIdx.x] = 0u;
}

__global__ __launch_bounds__(SIMT, 4)
void k_fused(const float* __restrict__ H,
             int* __restrict__ edge_cnt, uint32_t* __restrict__ edge_words,
             unsigned long long* __restrict__ uv, unsigned* __restrict__ cnt,
             const float* __restrict__ x,
             const float* __restrict__ beta, const float* __restrict__ gamma_,
             float* __restrict__ out, StepKeys keys) {
  const int tid = threadIdx.x;

  if (blockIdx.x > 0) {
    // ---------------- scan role: RPB consecutive (t,e) rows of H ----------------
    const int base  = (blockIdx.x - 1) * RPB;   // first global row
    const int t     = base / EE;                // same t for all RPB rows
    const int ebase = base - t * EE;            // first e

    // Issue ALL rows' loads upfront: 15 independent float4 loads per thread,
    // statically indexed (stays in VGPRs, ~60 data regs). 200 KB in flight/CU.
    const float4* h0 = reinterpret_cast<const float4*>(H + (size_t)base * NN);
    const bool has2 = (tid + 2048) < (NN / 4);  // tid < 452
    float4 v[RPB][3];
#pragma unroll
    for (int r = 0; r < RPB; ++r) {
      const float4* hrow = h0 + (size_t)r * (NN / 4);
      v[r][0] = hrow[tid];
      v[r][1] = hrow[tid + 1024];
      v[r][2] = has2 ? hrow[tid + 2048] : make_float4(0.f, 0.f, 0.f, 0.f);
    }

    // rand duty: rows with e < RBLK publish this step's uniforms. RPB=5 and
    // RBLK=10 => duty blocks have ebase 0 or 5 (all RPB rows are duty rows).
    // Runs here so the threefry VALU work hides under the load latency.
    if (ebase < RBLK) {
#pragma unroll
      for (int r = 0; r < RPB; ++r) {
        int e = ebase + r;
        int n = e * SIMT + tid;
        if (n < NN) {
          uint32_t a, b;
          tf2x32(keys.k1a[t], keys.k1b[t], 0u, (uint32_t)n, a, b);
          uint32_t b1 = __float_as_uint(bits_to_uniform(a ^ b));
          tf2x32(keys.k2a[t], keys.k2b[t], 0u, (uint32_t)n, a, b);
          uint32_t b2 = __float_as_uint(bits_to_uniform(a ^ b));
          unsigned long long raw = (unsigned long long)b1 | ((unsigned long long)b2 << 32);
          AST(&uv[(size_t)t * NN + n], raw);
        }
      }
    }

    __shared__ int scnt;
    __shared__ uint16_t list[CAP_E];
#define PROC(vv, b4) do { \
    if ((vv).x != 0.f) { int p = atomicAdd(&scnt, 1); if (p < CAP_E) list[p] = (uint16_t)((b4) + 0); } \
    if ((vv).y != 0.f) { int p = atomicAdd(&scnt, 1); if (p < CAP_E) list[p] = (uint16_t)((b4) + 1); } \
    if ((vv).z != 0.f) { int p = atomicAdd(&scnt, 1); if (p < CAP_E) list[p] = (uint16_t)((b4) + 2); } \
    if ((vv).w != 0.f) { int p = atomicAdd(&scnt, 1); if (p < CAP_E) list[p] = (uint16_t)((b4) + 3); } \
  } while (0)

#pragma unroll
    for (int r = 0; r < RPB; ++r) {
      if (r > 0) bar_lds();       // prev row's publish reads of scnt/list done
      if (tid == 0) scnt = 0;
      bar_lds();                  // scnt reset visible (LDS-only: loads stay in flight)
      PROC(v[r][0], 4 * tid);     // compiler waits vmcnt only for row r's regs
      PROC(v[r][1], 4 * (tid + 1024));
      if (has2) PROC(v[r][2], 4 * (tid + 2048));
      bar_lds();                  // list complete
      int c = scnt < CAP_E ? scnt : CAP_E;
      const int e = ebase + r;
      if (tid == 0) AST(&edge_cnt[t * EE + e], c);
      int words = (c + 1) >> 1;
      int wmax = words > PREW ? words : PREW;  // sentinel-pad so sim prefetches blindly
      if (tid < wmax) {
        uint32_t lo = (2 * tid     < c) ? (uint32_t)list[2 * tid]     : 0xFFFFu;
        uint32_t hi = (2 * tid + 1 < c) ? (uint32_t)list[2 * tid + 1] : 0xFFFFu;
        AST(&edge_words[((size_t)t * WPR + tid) * EE + e], lo | (hi << 16));
      }
      // stores are fire-and-forget; drained once for the whole block below
    }
#undef PROC
    __syncthreads();  // compiler emits s_waitcnt vmcnt(0): all atomic stores at MALL
    if (tid == 0)
      __hip_atomic_fetch_add(&cnt[t], (unsigned)RPB, __ATOMIC_RELAXED, __HIP_MEMORY_SCOPE_AGENT);
    return;
  }

  // ---------------- sim role (block 0, one CU) ----------------
  // nvst[n]: bits 0-15 = two-hop infected count (exact ints), bits 16-17 = state code.
  __shared__ int nvst[NN];   // 40 KB

  float p0[NPT], p1[NPT], p2[NPT], bet[NPT], gam[NPT];
#pragma unroll
  for (int k = 0; k < NPT; ++k) {
    int n = tid + k * SIMT;
    if (n < NN) {
      float x0 = x[n * 3 + 0], x1 = x[n * 3 + 1], x2 = x[n * 3 + 2];
      p0[k] = x0; p1[k] = x1; p2[k] = x2;
      int st = (x1 == 1.f) ? 1 : ((x0 == 1.f) ? 0 : 2);
      nvst[n] = st << 16;
      bet[k] = beta[n]; gam[k] = gamma_[n];
      out[n * 3 + 0] = x0; out[n * 3 + 1] = x1; out[n * 3 + 2] = x2;
      out[S_OFF + n * 3 + 0] = x0; out[S_OFF + n * 3 + 1] = x1; out[S_OFF + n * 3 + 2] = x2;
    }
  }
  bar_lds();

  for (int t = 0; t < TS; ++t) {
    // wait for all 1000 producer rows of step t (relaxed spin: no cache ops)
    if (tid == 0) {
      while (ALD(&cnt[t]) < (unsigned)EE) __builtin_amdgcn_s_sleep(8);
    }
    bar_lds();  // barrier A: flag seen; also orders prev node-phase nvst writes

    // preload uniforms for step t (now published) - 10 independent 8B MALL loads
    float u1r[NPT], u2r[NPT];
#pragma unroll
    for (int k = 0; k < NPT; ++k) {
      int n = tid + k * SIMT;
      if (n < NN) {
        unsigned long long raw = ALD(&uv[(size_t)t * NN + n]);
        u1r[k] = __uint_as_float((uint32_t)raw);
        u2r[k] = __uint_as_float((uint32_t)(raw >> 32));
      }
    }

    // edge phase: s = #infected members; scatter s into members' nvst low bits
    if (tid < EE) {
      const uint32_t* wb = edge_words + (size_t)t * WPR * EE + tid;
      int ec = ALD(&edge_cnt[t * EE + tid]); if (ec > CAP_E) ec = CAP_E;
      uint32_t w[PREW];
#pragma unroll
      for (int j = 0; j < PREW; ++j) w[j] = ALD(&wb[(size_t)j * EE]);  // independent
      int words = (ec + 1) >> 1;
      int s = 0;
#pragma unroll
      for (int j = 0; j < PREW; ++j) {
        uint32_t lo = w[j] & 0xFFFFu, hi = w[j] >> 16;
        if (lo != 0xFFFFu) s += ((nvst[lo] >> 16) == 1) ? 1 : 0;
        if (hi != 0xFFFFu) s += ((nvst[hi] >> 16) == 1) ? 1 : 0;
      }
      for (int j = PREW; j < words; ++j) {   // rare tail (ec > 16)
        uint32_t ww = ALD(&wb[(size_t)j * EE]);
        uint32_t lo = ww & 0xFFFFu, hi = ww >> 16;
        if (lo != 0xFFFFu) s += ((nvst[lo] >> 16) == 1) ? 1 : 0;
        if (hi != 0xFFFFu) s += ((nvst[hi] >> 16) == 1) ? 1 : 0;
      }
      if (s > 0) {  // adds can't carry into bit 16 (max sum 48000 < 65536)
#pragma unroll
        for (int j = 0; j < PREW; ++j) {
          uint32_t lo = w[j] & 0xFFFFu, hi = w[j] >> 16;
          if (lo != 0xFFFFu) atomicAdd(&nvst[lo], s);
          if (hi != 0xFFFFu) atomicAdd(&nvst[hi], s);
        }
        for (int j = PREW; j < words; ++j) {
          uint32_t ww = ALD(&wb[(size_t)j * EE]);
          uint32_t lo = ww & 0xFFFFu, hi = ww >> 16;
          if (lo != 0xFFFFu) atomicAdd(&nvst[lo], s);
          if (hi != 0xFFFFu) atomicAdd(&nvst[hi], s);
        }
      }
    }
    bar_lds();  // barrier B: nvst complete

    // node phase: advance p in regs, draw transitions, write rows, reset nvst
    float* po = out + (size_t)(t + 1) * ROW;
    float* so = out + S_OFF + (size_t)(t + 1) * ROW;
#pragma unroll
    for (int k = 0; k < NPT; ++k) {
      int n = tid + k * SIMT;
      if (n < NN) {
        int wv = nvst[n];
        int v  = wv & 0xFFFF;
        int st = wv >> 16;
        float s1 = (st == 1) ? 1.f : 0.f;
        float new_cases = __fmul_rn(bet[k], (float)v);
        float new_rec   = __fmul_rn(gam[k], s1);
        float q0 = fminf(1.f, fmaxf(0.f, __fsub_rn(p0[k], new_cases)));
        float q1 = fminf(1.f, fmaxf(0.f, __fsub_rn(__fadd_rn(p1[k], new_cases), new_rec)));
        float q2 = fminf(1.f, fmaxf(0.f, __fadd_rn(p2[k], new_rec)));
        p0[k] = q0; p1[k] = q1; p2[k] = q2;

        bool was_S  = (st == 0);
        bool was_I  = (st == 1);
        bool s_to_I = was_S && (u1r[k] < q1);
        bool i_event = was_I && (u1r[k] < q2);
        bool u2lt   = (u2r[k] < 0.5f);
        bool i_to_R = i_event && u2lt;
        bool i_to_S = i_event && !u2lt;
        bool new_S = (was_S && !s_to_I) || i_to_S;
        bool new_I = s_to_I || (was_I && !i_event);
        bool new_R = (!was_S && !was_I) || i_to_R;

        po[n * 3 + 0] = q0; po[n * 3 + 1] = q1; po[n * 3 + 2] = q2;
        so[n * 3 + 0] = new_S ? 1.f : 0.f;
        so[n * 3 + 1] = new_I ? 1.f : 0.f;
        so[n * 3 + 2] = new_R ? 1.f : 0.f;
        nvst[n] = (new_I ? 1 : (new_S ? 0 : 2)) << 16;  // reset count + new state
      }
    }
    // next iteration's barrier A orders these nvst writes vs next edge phase
  }
}

extern "C" void kernel_launch(void* const* d_in, const int* in_sizes, int n_in,
                              void* d_out, int out_size, void* d_ws, size_t ws_size,
                              hipStream_t stream) {
  const float* x      = (const float*)d_in[0];
  const float* H      = (const float*)d_in[1];
  const float* beta   = (const float*)d_in[2];
  const float* gamma_ = (const float*)d_in[3];
  float* out = (float*)d_out;

  // key chain: key0 = jax.random.key(42) = (0,42); split(key,3) partitionable:
  // subkey i = threefry(key, (0,i)); carry = subkey 0.
  StepKeys keys;
  uint32_t key0 = 0u, key1 = 42u;
  for (int t = 0; t < TS; ++t) {
    uint32_t a0, b0, a1, b1, a2, b2;
    tf2x32(key0, key1, 0u, 0u, a0, b0);
    tf2x32(key0, key1, 0u, 1u, a1, b1);
    tf2x32(key0, key1, 0u, 2u, a2, b2);
    keys.k1a[t] = a1; keys.k1b[t] = b1; keys.k2a[t] = a2; keys.k2b[t] = b2;
    key0 = a0; key1 = b0;
  }

  // workspace layout (~5.2 MB)
  size_t off = 0;
  auto take = [&](size_t bytes) { size_t o = off; off += (bytes + 255) & ~(size_t)255; return o; };
  size_t o_ec = take((size_t)TS * EE * sizeof(int));
  size_t o_ew = take((size_t)TS * WPR * EE * sizeof(uint32_t));
  size_t o_uv = take((size_t)TS * NN * sizeof(unsigned long long));
  size_t o_ct = take((size_t)TS * sizeof(unsigned));

  int*      edge_cnt   = (int*)((char*)d_ws + o_ec);
  uint32_t* edge_words = (uint32_t*)((char*)d_ws + o_ew);
  unsigned long long* uv = (unsigned long long*)((char*)d_ws + o_uv);
  unsigned* cnt        = (unsigned*)((char*)d_ws + o_ct);

  k_zero<<<1, 64, 0, stream>>>(cnt);
  k_fused<<<1 + (TS * EE) / RPB, SIMT, 0, stream>>>(H, edge_cnt, edge_words, uv, cnt,
                                                    x, beta, gamma_, out, keys);
}